// Round 1
// baseline (208.043 us; speedup 1.0000x reference)
//
#include <hip/hip_runtime.h>
#include <stdint.h>

// ---- problem constants ----
#define B_   8
#define SQ_  512
#define SK_  512
#define H_   768
#define NH_  12
#define DH_  64
#define BH_  (B_*NH_)          // 96 (b,h) pairs
#define M_   (B_*SQ_)          // 4096 rows for both hidden and context
#define NTOT (3*H_)            // 2304 fused QKV output columns

typedef __attribute__((ext_vector_type(8))) short short8;
typedef __attribute__((ext_vector_type(4))) float floatx4;
typedef __attribute__((ext_vector_type(4))) unsigned int uint4v;
typedef __attribute__((ext_vector_type(4))) unsigned short ushort4v;

#define MFMA16(a, b, c) __builtin_amdgcn_mfma_f32_16x16x32_bf16((a), (b), (c), 0, 0, 0)

__device__ __forceinline__ unsigned short f2b(float f) {   // fp32 -> bf16 bits (RNE)
  union { float f; unsigned u; } c; c.f = f;
  unsigned r = (c.u + 0x7fffu + ((c.u >> 16) & 1u)) >> 16;
  return (unsigned short)r;
}
__device__ __forceinline__ unsigned short f2h(float f) {   // fp32 -> fp16 bits
  union { _Float16 h; unsigned short u; } c; c.h = (_Float16)f;
  return c.u;
}
__device__ __forceinline__ float h2f(unsigned short u) {
  union { _Float16 h; unsigned short u; } c; c.u = u;
  return (float)c.h;
}
__device__ __forceinline__ short8 ld8(const unsigned short* p) {  // 16B vector load
  union { uint4v u; short8 s; } c;
  c.u = *(const uint4v*)p;
  return c.s;
}
__device__ __forceinline__ void st8(unsigned short* p, short8 v) {
  union { uint4v u; short8 s; } c; c.s = v;
  *(uint4v*)p = c.u;
}

// ---------------------------------------------------------------------------
// Kernel 1: pack fp32 inputs -> bf16 workspace (hidden, context, Wq|Wk|Wv, biases)
// ---------------------------------------------------------------------------
#define SEG_X   (M_*H_)          // 3145728 (hidden)
#define SEG_XC  (2*SEG_X)        // 6291456 (end of context)
#define SEG_W1  (H_*H_)          // 589824
#define SEG_WE  (SEG_XC + 3*SEG_W1)   // 8060928
#define SEG_BE  (SEG_WE + NTOT)  // 8063232

__global__ __launch_bounds__(256) void pack_kernel(
    const float* __restrict__ hid, const float* __restrict__ ctx,
    const float* __restrict__ Wq, const float* __restrict__ Wk, const float* __restrict__ Wv,
    const float* __restrict__ bq, const float* __restrict__ bk, const float* __restrict__ bv,
    unsigned short* __restrict__ Xh, unsigned short* __restrict__ Xc,
    unsigned short* __restrict__ Wa, float* __restrict__ Ba)
{
  int i = (blockIdx.x * 256 + threadIdx.x) * 4;
  if (i < SEG_X) {
    floatx4 v = *(const floatx4*)(hid + i);
    ushort4v o = { f2b(v.x), f2b(v.y), f2b(v.z), f2b(v.w) };
    *(ushort4v*)(Xh + i) = o;
  } else if (i < SEG_XC) {
    int j = i - SEG_X;
    floatx4 v = *(const floatx4*)(ctx + j);
    ushort4v o = { f2b(v.x), f2b(v.y), f2b(v.z), f2b(v.w) };
    *(ushort4v*)(Xc + j) = o;
  } else if (i < SEG_WE) {
    int j = i - SEG_XC;
    const float* src; int o;
    if (j < SEG_W1)        { src = Wq; o = j; }
    else if (j < 2*SEG_W1) { src = Wk; o = j - SEG_W1; }
    else                   { src = Wv; o = j - 2*SEG_W1; }
    floatx4 v = *(const floatx4*)(src + o);
    ushort4v ov = { f2b(v.x), f2b(v.y), f2b(v.z), f2b(v.w) };
    *(ushort4v*)(Wa + j) = ov;
  } else if (i < SEG_BE) {
    int j = i - SEG_WE;
    #pragma unroll
    for (int t = 0; t < 4; ++t) {
      int jj = j + t;
      float v = (jj < H_) ? bq[jj] : (jj < 2*H_) ? bk[jj - H_] : bv[jj - 2*H_];
      Ba[jj] = v;
    }
  }
}

// ---------------------------------------------------------------------------
// Kernel 2: P[q][k] = dot(pos[q], pos[k])  (512x512 fp32), tiny
// ---------------------------------------------------------------------------
__global__ __launch_bounds__(256) void pos_kernel(const float* __restrict__ pos,
                                                  float* __restrict__ P)
{
  int q = blockIdx.x;
  int t = threadIdx.x;
  __shared__ float pq[DH_];
  if (t < DH_) pq[t] = pos[q * DH_ + t];
  __syncthreads();
  for (int k = t; k < SK_; k += 256) {
    float s = 0.f;
    #pragma unroll
    for (int d = 0; d < DH_; ++d) s += pq[d] * pos[k * DH_ + d];
    P[q * SK_ + k] = s;
  }
}

// ---------------------------------------------------------------------------
// Kernel 3: fused QKV projection GEMM (bf16 MFMA), M=4096 x N=2304 x K=768
//   C = X @ W^T + b ; epilogue scatters into head layouts:
//     Q  -> qw[bh][s][d]  (bf16)
//     K  -> kw[bh][s][d] = k + pos_emb[s][d]  (bf16)   [folds pos_k]
//     V  -> vt[bh][d][s]  (bf16, transposed for PV B-operand)
// 128x128 block tile, 4 waves (2x2), each wave 64x64 via 4x4 MFMA tiles, BK=32.
// ---------------------------------------------------------------------------
__global__ __launch_bounds__(256) void qkv_gemm(
    const unsigned short* __restrict__ Xh, const unsigned short* __restrict__ Xc,
    const unsigned short* __restrict__ W,  const float* __restrict__ bias,
    const float* __restrict__ pos,
    unsigned short* __restrict__ qw, unsigned short* __restrict__ kw,
    unsigned short* __restrict__ vt)
{
  // 40 = 32 + 8 pad: row stride 80B = 5*16B (b128-aligned), bank stride 20 words -> 2-way (free)
  __shared__ unsigned short As[128][40];
  __shared__ unsigned short Bs[128][40];

  int bx = blockIdx.x;
  int bn = bx % 18, bm = bx / 18;          // 18 n-tiles, 32 m-tiles
  const unsigned short* X = (bn < 6) ? Xh : Xc;
  int m0 = bm * 128, n0 = bn * 128;

  int tid = threadIdx.x;
  int lane = tid & 63, wave = tid >> 6;
  int wm = (wave & 1) * 64, wn = (wave >> 1) * 64;
  int lc16 = lane & 15, quad = lane >> 4, kk = quad * 8;
  int lr = tid >> 2, lc = (tid & 3) * 8;   // staging: 64 rows x 4 chunks of 8

  floatx4 acc[4][4];
  #pragma unroll
  for (int i = 0; i < 4; ++i)
    #pragma unroll
    for (int j = 0; j < 4; ++j) acc[i][j] = (floatx4){0.f, 0.f, 0.f, 0.f};

  for (int k0 = 0; k0 < H_; k0 += 32) {
    uint4v a0 = *(const uint4v*)&X[(m0 + lr) * H_ + k0 + lc];
    uint4v a1 = *(const uint4v*)&X[(m0 + lr + 64) * H_ + k0 + lc];
    uint4v b0 = *(const uint4v*)&W[(n0 + lr) * H_ + k0 + lc];
    uint4v b1 = *(const uint4v*)&W[(n0 + lr + 64) * H_ + k0 + lc];
    __syncthreads();
    *(uint4v*)&As[lr][lc] = a0;
    *(uint4v*)&As[lr + 64][lc] = a1;
    *(uint4v*)&Bs[lr][lc] = b0;
    *(uint4v*)&Bs[lr + 64][lc] = b1;
    __syncthreads();

    short8 af[4], bf[4];
    #pragma unroll
    for (int i = 0; i < 4; ++i) af[i] = ld8(&As[wm + i * 16 + lc16][kk]);
    #pragma unroll
    for (int i = 0; i < 4; ++i) bf[i] = ld8(&Bs[wn + i * 16 + lc16][kk]);
    #pragma unroll
    for (int mi = 0; mi < 4; ++mi)
      #pragma unroll
      for (int ni = 0; ni < 4; ++ni)
        acc[mi][ni] = MFMA16(af[mi], bf[ni], acc[mi][ni]);
  }

  // epilogue: D layout col=lane&15, row=quad*4+r
  #pragma unroll
  for (int mi = 0; mi < 4; ++mi) {
    #pragma unroll
    for (int ni = 0; ni < 4; ++ni) {
      int gm0 = m0 + wm + mi * 16 + quad * 4;       // global row base (4 consecutive rows)
      int gn  = n0 + wn + ni * 16 + lc16;           // global col
      float bv = bias[gn];
      int bidx = gm0 >> 9;                           // batch (rows of 512)
      int s0   = gm0 & 511;
      if (gn < H_) {                                 // Q
        int h = gn >> 6, d = gn & 63;
        unsigned short* dst = qw + (((bidx * NH_ + h) << 9) + s0) * DH_ + d;
        #pragma unroll
        for (int r = 0; r < 4; ++r) dst[r * DH_] = f2b(acc[mi][ni][r] + bv);
      } else if (gn < 2 * H_) {                      // K (+ pos_k)
        int g = gn - H_;
        int h = g >> 6, d = g & 63;
        unsigned short* dst = kw + (((bidx * NH_ + h) << 9) + s0) * DH_ + d;
        #pragma unroll
        for (int r = 0; r < 4; ++r)
          dst[r * DH_] = f2b(acc[mi][ni][r] + bv + pos[(s0 + r) * DH_ + d]);
      } else {                                       // V -> transposed
        int g = gn - 2 * H_;
        int h = g >> 6, d = g & 63;
        ushort4v pk;
        #pragma unroll
        for (int r = 0; r < 4; ++r) pk[r] = f2b(acc[mi][ni][r] + bv);
        *(ushort4v*)(vt + ((bidx * NH_ + h) * DH_ + d) * SK_ + s0) = pk;
      }
    }
  }
}

// ---------------------------------------------------------------------------
// Kernel 4: attention. 1 block = one (b,h) and 64 q-rows. 4 waves x 16 rows.
//   scores = (q @ kpos^T + P) / 8 + maskbias -> fp16 LDS -> softmax ->
//   bf16 probs in-place -> out = (probs @ v) / rowsum
// ---------------------------------------------------------------------------
__global__ __launch_bounds__(256) void attn_kernel(
    const unsigned short* __restrict__ qw, const unsigned short* __restrict__ kw,
    const unsigned short* __restrict__ vt, const float* __restrict__ P,
    const int* __restrict__ mask, float* __restrict__ out)
{
  __shared__ unsigned short S[64][520];   // fp16 logits, then bf16 probs (row pad: 1040B stride)
  __shared__ float mb[SK_];
  __shared__ float red[64][4];
  __shared__ float rsum[64];

  int bx = blockIdx.x;
  int bh = bx >> 3, qt = bx & 7;
  int b = bh / NH_, h = bh - b * NH_;
  int tid = threadIdx.x, lane = tid & 63, wave = tid >> 6;
  int lc16 = lane & 15, quad = lane >> 4, kk = quad * 8;

  for (int i = tid; i < SK_; i += 256)
    mb[i] = mask[(b << 9) + i] ? 0.0f : -30000.0f;

  // A-frags (q rows) held for whole QK^T phase
  const unsigned short* qbase = qw + ((bh << 9) + qt * 64 + wave * 16) * DH_;
  short8 a0 = ld8(qbase + lc16 * DH_ + kk);
  short8 a1 = ld8(qbase + lc16 * DH_ + 32 + kk);
  __syncthreads();   // mask bias ready

  const unsigned short* kbase = kw + ((bh << 9)) * DH_;
  int qrow_l0 = wave * 16 + quad * 4;
  int qrow_g0 = qt * 64 + qrow_l0;
  for (int nt = 0; nt < 32; ++nt) {
    const unsigned short* kb = kbase + nt * 16 * DH_;
    short8 b0 = ld8(kb + lc16 * DH_ + kk);
    short8 b1 = ld8(kb + lc16 * DH_ + 32 + kk);
    floatx4 c = (floatx4){0.f, 0.f, 0.f, 0.f};
    c = MFMA16(a0, b0, c);
    c = MFMA16(a1, b1, c);
    int kcol = nt * 16 + lc16;
    float mbias = mb[kcol];
    #pragma unroll
    for (int r = 0; r < 4; ++r) {
      float s = (c[r] + P[(qrow_g0 + r) * SK_ + kcol]) * 0.125f + mbias;
      S[qrow_l0 + r][kcol] = f2h(s);
    }
  }
  __syncthreads();

  // softmax: 4 threads per row, 128 elems each
  int row = tid >> 2, part = tid & 3;
  unsigned short* Sr = &S[row][part * 128];
  float mx = -3.0e38f;
  #pragma unroll 4
  for (int i = 0; i < 16; ++i) {
    short8 v = ld8(Sr + 8 * i);
    #pragma unroll
    for (int j = 0; j < 8; ++j) mx = fmaxf(mx, h2f((unsigned short)v[j]));
  }
  red[row][part] = mx;
  __syncthreads();
  mx = fmaxf(fmaxf(red[row][0], red[row][1]), fmaxf(red[row][2], red[row][3]));
  __syncthreads();
  float sm = 0.f;
  #pragma unroll 4
  for (int i = 0; i < 16; ++i) {
    short8 v = ld8(Sr + 8 * i);
    short8 o;
    #pragma unroll
    for (int j = 0; j < 8; ++j) {
      float e = __expf(h2f((unsigned short)v[j]) - mx);
      sm += e;
      o[j] = (short)f2b(e);            // unnormalized prob in [0,1]
    }
    st8(Sr + 8 * i, o);
  }
  red[row][part] = sm;
  __syncthreads();
  if (part == 0) rsum[row] = red[row][0] + red[row][1] + red[row][2] + red[row][3];
  __syncthreads();

  // PV: per wave 16 q-rows, N=64 (4 d-tiles), K=512 (16 steps)
  const unsigned short* vb0 = vt + bh * DH_ * SK_;
  floatx4 o[4];
  #pragma unroll
  for (int i = 0; i < 4; ++i) o[i] = (floatx4){0.f, 0.f, 0.f, 0.f};
  for (int ks = 0; ks < 16; ++ks) {
    short8 pa = ld8(&S[wave * 16 + lc16][ks * 32 + kk]);
    #pragma unroll
    for (int dt = 0; dt < 4; ++dt) {
      short8 vf = ld8(vb0 + (dt * 16 + lc16) * SK_ + ks * 32 + kk);
      o[dt] = MFMA16(pa, vf, o[dt]);
    }
  }

  float inv[4];
  #pragma unroll
  for (int r = 0; r < 4; ++r) inv[r] = 1.0f / rsum[qrow_l0 + r];
  #pragma unroll
  for (int dt = 0; dt < 4; ++dt) {
    #pragma unroll
    for (int r = 0; r < 4; ++r) {
      int s = qt * 64 + qrow_l0 + r;
      out[((b << 9) + s) * H_ + h * DH_ + dt * 16 + lc16] = o[dt][r] * inv[r];
    }
  }
}

// ---------------------------------------------------------------------------
// host launcher
// ---------------------------------------------------------------------------
extern "C" void kernel_launch(void* const* d_in, const int* in_sizes, int n_in,
                              void* d_out, int out_size, void* d_ws, size_t ws_size,
                              hipStream_t stream) {
  (void)in_sizes; (void)n_in; (void)out_size; (void)ws_size;
  const float* hid  = (const float*)d_in[0];
  const float* ctx  = (const float*)d_in[1];
  const int*   mask = (const int*)d_in[2];
  const float* Wq   = (const float*)d_in[3];
  const float* bq   = (const float*)d_in[4];
  const float* Wk   = (const float*)d_in[5];
  const float* bk   = (const float*)d_in[6];
  const float* Wv   = (const float*)d_in[7];
  const float* bv   = (const float*)d_in[8];
  const float* pos  = (const float*)d_in[9];

  char* ws = (char*)d_ws;
  size_t off = 0;
  auto alloc = [&](size_t bytes) { char* p = ws + off; off = (off + bytes + 255) & ~(size_t)255; return p; };
  unsigned short* Xh = (unsigned short*)alloc((size_t)SEG_X * 2);
  unsigned short* Xc = (unsigned short*)alloc((size_t)SEG_X * 2);
  unsigned short* Wa = (unsigned short*)alloc((size_t)3 * SEG_W1 * 2);
  float*          Ba = (float*)alloc((size_t)NTOT * 4);
  unsigned short* qw = (unsigned short*)alloc((size_t)BH_ * SQ_ * DH_ * 2);
  unsigned short* kw = (unsigned short*)alloc((size_t)BH_ * SK_ * DH_ * 2);
  unsigned short* vt = (unsigned short*)alloc((size_t)BH_ * DH_ * SK_ * 2);
  float*          Pp = (float*)alloc((size_t)SQ_ * SK_ * 4);

  int pack_blocks = (SEG_BE / 4 + 255) / 256;
  pack_kernel<<<pack_blocks, 256, 0, stream>>>(hid, ctx, Wq, Wk, Wv, bq, bk, bv, Xh, Xc, Wa, Ba);
  pos_kernel<<<SQ_, 256, 0, stream>>>(pos, Pp);
  qkv_gemm<<<32 * 18, 256, 0, stream>>>(Xh, Xc, Wa, Ba, pos, qw, kw, vt);
  attn_kernel<<<BH_ * 8, 256, 0, stream>>>(qw, kw, vt, Pp, mask, (float*)d_out);
}

// Round 2
// 202.640 us; speedup vs baseline: 1.0267x; 1.0267x over previous
//
#include <hip/hip_runtime.h>
#include <stdint.h>

// ---- problem constants ----
#define B_   8
#define SQ_  512
#define SK_  512
#define H_   768
#define NH_  12
#define DH_  64
#define BH_  (B_*NH_)          // 96 (b,h) pairs
#define M_   (B_*SQ_)          // 4096 rows for both hidden and context
#define NTOT (3*H_)            // 2304 fused QKV output columns

typedef __attribute__((ext_vector_type(8))) short short8;
typedef __attribute__((ext_vector_type(4))) float floatx4;
typedef __attribute__((ext_vector_type(4))) unsigned int uint4v;
typedef __attribute__((ext_vector_type(4))) unsigned short ushort4v;

#define MFMA16(a, b, c) __builtin_amdgcn_mfma_f32_16x16x32_bf16((a), (b), (c), 0, 0, 0)

__device__ __forceinline__ unsigned short f2b(float f) {   // fp32 -> bf16 bits (RNE)
  union { float f; unsigned u; } c; c.f = f;
  unsigned r = (c.u + 0x7fffu + ((c.u >> 16) & 1u)) >> 16;
  return (unsigned short)r;
}
__device__ __forceinline__ unsigned short f2h(float f) {   // fp32 -> fp16 bits
  union { _Float16 h; unsigned short u; } c; c.h = (_Float16)f;
  return c.u;
}
__device__ __forceinline__ float h2f(unsigned short u) {
  union { _Float16 h; unsigned short u; } c; c.u = u;
  return (float)c.h;
}
__device__ __forceinline__ short8 ld8(const unsigned short* p) {  // 16B vector load
  union { uint4v u; short8 s; } c;
  c.u = *(const uint4v*)p;
  return c.s;
}
__device__ __forceinline__ void st8(unsigned short* p, short8 v) {
  union { uint4v u; short8 s; } c; c.s = v;
  *(uint4v*)p = c.u;
}

// ---------------------------------------------------------------------------
// Kernel 1: pack fp32 inputs -> bf16 workspace (hidden, context, W, pos, biases)
// ---------------------------------------------------------------------------
#define SEG_X   (M_*H_)          // 3145728 (hidden)
#define SEG_XC  (2*SEG_X)        // 6291456 (end of context)
#define SEG_W1  (H_*H_)          // 589824
#define SEG_WE  (SEG_XC + 3*SEG_W1)   // 8060928
#define SEG_BE  (SEG_WE + NTOT)  // 8063232
#define SEG_PE  (SEG_BE + SQ_*DH_)    // 8096000 (pos bf16)

__global__ __launch_bounds__(256) void pack_kernel(
    const float* __restrict__ hid, const float* __restrict__ ctx,
    const float* __restrict__ Wq, const float* __restrict__ Wk, const float* __restrict__ Wv,
    const float* __restrict__ bq, const float* __restrict__ bk, const float* __restrict__ bv,
    const float* __restrict__ pos,
    unsigned short* __restrict__ Xh, unsigned short* __restrict__ Xc,
    unsigned short* __restrict__ Wa, float* __restrict__ Ba,
    unsigned short* __restrict__ Pb)
{
  int i = (blockIdx.x * 256 + threadIdx.x) * 4;
  if (i < SEG_X) {
    floatx4 v = *(const floatx4*)(hid + i);
    ushort4v o = { f2b(v.x), f2b(v.y), f2b(v.z), f2b(v.w) };
    *(ushort4v*)(Xh + i) = o;
  } else if (i < SEG_XC) {
    int j = i - SEG_X;
    floatx4 v = *(const floatx4*)(ctx + j);
    ushort4v o = { f2b(v.x), f2b(v.y), f2b(v.z), f2b(v.w) };
    *(ushort4v*)(Xc + j) = o;
  } else if (i < SEG_WE) {
    int j = i - SEG_XC;
    const float* src; int o;
    if (j < SEG_W1)        { src = Wq; o = j; }
    else if (j < 2*SEG_W1) { src = Wk; o = j - SEG_W1; }
    else                   { src = Wv; o = j - 2*SEG_W1; }
    floatx4 v = *(const floatx4*)(src + o);
    ushort4v ov = { f2b(v.x), f2b(v.y), f2b(v.z), f2b(v.w) };
    *(ushort4v*)(Wa + j) = ov;
  } else if (i < SEG_BE) {
    int j = i - SEG_WE;
    #pragma unroll
    for (int t = 0; t < 4; ++t) {
      int jj = j + t;
      float v = (jj < H_) ? bq[jj] : (jj < 2*H_) ? bk[jj - H_] : bv[jj - 2*H_];
      Ba[jj] = v;
    }
  } else if (i < SEG_PE) {
    int j = i - SEG_BE;
    floatx4 v = *(const floatx4*)(pos + j);
    ushort4v o = { f2b(v.x), f2b(v.y), f2b(v.z), f2b(v.w) };
    *(ushort4v*)(Pb + j) = o;
  }
}

// ---------------------------------------------------------------------------
// Kernel 2: fused QKV projection GEMM (bf16 MFMA), M=4096 x N=2304 x K=768
//   C = X @ W^T + b ; epilogue scatters into head layouts:
//     Q  -> qw[bh][s][d]  (bf16)
//     K  -> kw[bh][s][d] = k + pos_emb[s][d]  (bf16)   [folds pos_k]
//     V  -> vt[bh][d][s]  (bf16, transposed for PV B-operand)
// 128x128 block tile, 4 waves (2x2), each wave 64x64 via 4x4 MFMA tiles, BK=64.
// ---------------------------------------------------------------------------
__global__ __launch_bounds__(256) void qkv_gemm(
    const unsigned short* __restrict__ Xh, const unsigned short* __restrict__ Xc,
    const unsigned short* __restrict__ W,  const float* __restrict__ bias,
    const float* __restrict__ pos,
    unsigned short* __restrict__ qw, unsigned short* __restrict__ kw,
    unsigned short* __restrict__ vt)
{
  // 72 = 64 + 8 pad: row stride 144B, bank stride 36 words -> balanced b128 reads
  __shared__ unsigned short As[128][72];
  __shared__ unsigned short Bs[128][72];

  int bx = blockIdx.x;
  int bn = bx % 18, bm = bx / 18;          // 18 n-tiles, 32 m-tiles
  const unsigned short* X = (bn < 6) ? Xh : Xc;
  int m0 = bm * 128, n0 = bn * 128;

  int tid = threadIdx.x;
  int lane = tid & 63, wave = tid >> 6;
  int wm = (wave & 1) * 64, wn = (wave >> 1) * 64;
  int lc16 = lane & 15, quad = lane >> 4, kk = quad * 8;
  int srow = tid >> 3, sch = (tid & 7) * 8;   // staging: 32 rows x 8 chunks of 8

  floatx4 acc[4][4];
  #pragma unroll
  for (int i = 0; i < 4; ++i)
    #pragma unroll
    for (int j = 0; j < 4; ++j) acc[i][j] = (floatx4){0.f, 0.f, 0.f, 0.f};

  for (int k0 = 0; k0 < H_; k0 += 64) {
    uint4v a[4], b[4];
    #pragma unroll
    for (int rp = 0; rp < 4; ++rp) {
      a[rp] = *(const uint4v*)&X[(m0 + srow + rp * 32) * H_ + k0 + sch];
      b[rp] = *(const uint4v*)&W[(n0 + srow + rp * 32) * H_ + k0 + sch];
    }
    __syncthreads();
    #pragma unroll
    for (int rp = 0; rp < 4; ++rp) {
      *(uint4v*)&As[srow + rp * 32][sch] = a[rp];
      *(uint4v*)&Bs[srow + rp * 32][sch] = b[rp];
    }
    __syncthreads();

    #pragma unroll
    for (int s = 0; s < 2; ++s) {
      short8 af[4], bf[4];
      #pragma unroll
      for (int i = 0; i < 4; ++i) af[i] = ld8(&As[wm + i * 16 + lc16][s * 32 + kk]);
      #pragma unroll
      for (int i = 0; i < 4; ++i) bf[i] = ld8(&Bs[wn + i * 16 + lc16][s * 32 + kk]);
      #pragma unroll
      for (int mi = 0; mi < 4; ++mi)
        #pragma unroll
        for (int ni = 0; ni < 4; ++ni)
          acc[mi][ni] = MFMA16(af[mi], bf[ni], acc[mi][ni]);
    }
  }

  // epilogue: D layout col=lane&15, row=quad*4+r
  #pragma unroll
  for (int mi = 0; mi < 4; ++mi) {
    #pragma unroll
    for (int ni = 0; ni < 4; ++ni) {
      int gm0 = m0 + wm + mi * 16 + quad * 4;       // global row base (4 consecutive rows)
      int gn  = n0 + wn + ni * 16 + lc16;           // global col
      float bv = bias[gn];
      int bidx = gm0 >> 9;                           // batch (rows of 512)
      int s0   = gm0 & 511;
      if (gn < H_) {                                 // Q
        int h = gn >> 6, d = gn & 63;
        unsigned short* dst = qw + (((bidx * NH_ + h) << 9) + s0) * DH_ + d;
        #pragma unroll
        for (int r = 0; r < 4; ++r) dst[r * DH_] = f2b(acc[mi][ni][r] + bv);
      } else if (gn < 2 * H_) {                      // K (+ pos_k)
        int g = gn - H_;
        int h = g >> 6, d = g & 63;
        unsigned short* dst = kw + (((bidx * NH_ + h) << 9) + s0) * DH_ + d;
        #pragma unroll
        for (int r = 0; r < 4; ++r)
          dst[r * DH_] = f2b(acc[mi][ni][r] + bv + pos[(s0 + r) * DH_ + d]);
      } else {                                       // V -> transposed
        int g = gn - 2 * H_;
        int h = g >> 6, d = g & 63;
        ushort4v pk;
        #pragma unroll
        for (int r = 0; r < 4; ++r) pk[r] = f2b(acc[mi][ni][r] + bv);
        *(ushort4v*)(vt + ((bidx * NH_ + h) * DH_ + d) * SK_ + s0) = pk;
      }
    }
  }
}

// ---------------------------------------------------------------------------
// Kernel 3: attention. 1 block = one (b,h) and 32 q-rows. 4 waves.
//   scores = (q @ (k+pos_k)^T + pos_q @ pos_k^T) / 8 + maskbias   (all MFMA)
//   -> fp16 LDS -> softmax -> bf16 probs in-place -> out = (probs @ v)/rowsum
//   QK: waves split 2(q-halves) x 2(k-halves); PV: 2(q) x 2(d).
// ---------------------------------------------------------------------------
__global__ __launch_bounds__(256) void attn_kernel(
    const unsigned short* __restrict__ qw, const unsigned short* __restrict__ kw,
    const unsigned short* __restrict__ vt, const unsigned short* __restrict__ posb,
    const int* __restrict__ mask, float* __restrict__ out)
{
  __shared__ unsigned short S[32][520];   // fp16 logits, then bf16 probs
  __shared__ float mb[SK_];
  __shared__ float red[32][8];
  __shared__ float rsum[32];

  int bx = blockIdx.x;
  int bh = bx >> 4, qt = bx & 15;          // 16 q-tiles of 32 rows
  int b = bh / NH_, h = bh - b * NH_;
  int tid = threadIdx.x, lane = tid & 63, wave = tid >> 6;
  int lc16 = lane & 15, quad = lane >> 4, kk = quad * 8;
  int qh = (wave & 1) * 16;                // q-row half within tile
  int kh = (wave >> 1) * 256;              // k half (QK phase)
  int dh = (wave >> 1) * 32;               // d half (PV phase)

  for (int i = tid; i < SK_; i += 256)
    mb[i] = mask[(b << 9) + i] ? 0.0f : -30000.0f;

  // A-frags (held for whole QK^T phase): q rows + pos_q rows
  const unsigned short* qbase = qw + ((bh << 9) + qt * 32 + qh) * DH_;
  const unsigned short* pqb   = posb + (qt * 32 + qh) * DH_;
  short8 aq0 = ld8(qbase + lc16 * DH_ + kk);
  short8 aq1 = ld8(qbase + lc16 * DH_ + 32 + kk);
  short8 ap0 = ld8(pqb + lc16 * DH_ + kk);
  short8 ap1 = ld8(pqb + lc16 * DH_ + 32 + kk);
  __syncthreads();   // mask bias ready

  int qrl = qh + quad * 4;                 // local q-row base for C layout
  #pragma unroll 2
  for (int nt = 0; nt < 16; ++nt) {
    int kcol = kh + nt * 16;
    const unsigned short* kb = kw + ((bh << 9) + kcol) * DH_;
    const unsigned short* pb = posb + kcol * DH_;
    short8 b0 = ld8(kb + lc16 * DH_ + kk);
    short8 b1 = ld8(kb + lc16 * DH_ + 32 + kk);
    short8 p0 = ld8(pb + lc16 * DH_ + kk);
    short8 p1 = ld8(pb + lc16 * DH_ + 32 + kk);
    floatx4 c = (floatx4){0.f, 0.f, 0.f, 0.f};
    c = MFMA16(aq0, b0, c);
    c = MFMA16(aq1, b1, c);
    c = MFMA16(ap0, p0, c);
    c = MFMA16(ap1, p1, c);
    float mbias = mb[kcol + lc16];
    #pragma unroll
    for (int r = 0; r < 4; ++r)
      S[qrl + r][kcol + lc16] = f2h(c[r] * 0.125f + mbias);
  }
  __syncthreads();

  // softmax: 8 threads per row, 64 elems each
  int row = tid >> 3, part = tid & 7;
  unsigned short* Sr = &S[row][part * 64];
  float mx = -3.0e38f;
  #pragma unroll
  for (int i = 0; i < 8; ++i) {
    short8 v = ld8(Sr + 8 * i);
    #pragma unroll
    for (int j = 0; j < 8; ++j) mx = fmaxf(mx, h2f((unsigned short)v[j]));
  }
  red[row][part] = mx;
  __syncthreads();
  #pragma unroll
  for (int p = 0; p < 8; ++p) mx = fmaxf(mx, red[row][p]);
  __syncthreads();
  float sm = 0.f;
  #pragma unroll
  for (int i = 0; i < 8; ++i) {
    short8 v = ld8(Sr + 8 * i);
    short8 o;
    #pragma unroll
    for (int j = 0; j < 8; ++j) {
      float e = __expf(h2f((unsigned short)v[j]) - mx);
      sm += e;
      o[j] = (short)f2b(e);            // unnormalized prob in [0,1]
    }
    st8(Sr + 8 * i, o);
  }
  red[row][part] = sm;
  __syncthreads();
  if (part == 0) {
    float s = 0.f;
    #pragma unroll
    for (int p = 0; p < 8; ++p) s += red[row][p];
    rsum[row] = s;
  }
  __syncthreads();

  // PV: per wave 16 q-rows x 32 d, K=512 (16 steps)
  const unsigned short* vb0 = vt + (bh * DH_ + dh) * SK_;
  floatx4 o[2];
  o[0] = (floatx4){0.f, 0.f, 0.f, 0.f};
  o[1] = (floatx4){0.f, 0.f, 0.f, 0.f};
  #pragma unroll 2
  for (int ks = 0; ks < 16; ++ks) {
    short8 pa = ld8(&S[qh + lc16][ks * 32 + kk]);
    #pragma unroll
    for (int dt = 0; dt < 2; ++dt) {
      short8 vf = ld8(vb0 + (dt * 16 + lc16) * SK_ + ks * 32 + kk);
      o[dt] = MFMA16(pa, vf, o[dt]);
    }
  }

  float inv[4];
  #pragma unroll
  for (int r = 0; r < 4; ++r) inv[r] = 1.0f / rsum[qrl + r];
  #pragma unroll
  for (int dt = 0; dt < 2; ++dt) {
    #pragma unroll
    for (int r = 0; r < 4; ++r) {
      int s = qt * 32 + qrl + r;
      out[((b << 9) + s) * H_ + h * DH_ + dh + dt * 16 + lc16] = o[dt][r] * inv[r];
    }
  }
}

// ---------------------------------------------------------------------------
// host launcher
// ---------------------------------------------------------------------------
extern "C" void kernel_launch(void* const* d_in, const int* in_sizes, int n_in,
                              void* d_out, int out_size, void* d_ws, size_t ws_size,
                              hipStream_t stream) {
  (void)in_sizes; (void)n_in; (void)out_size; (void)ws_size;
  const float* hid  = (const float*)d_in[0];
  const float* ctx  = (const float*)d_in[1];
  const int*   mask = (const int*)d_in[2];
  const float* Wq   = (const float*)d_in[3];
  const float* bq   = (const float*)d_in[4];
  const float* Wk   = (const float*)d_in[5];
  const float* bk   = (const float*)d_in[6];
  const float* Wv   = (const float*)d_in[7];
  const float* bv   = (const float*)d_in[8];
  const float* pos  = (const float*)d_in[9];

  char* ws = (char*)d_ws;
  size_t off = 0;
  auto alloc = [&](size_t bytes) { char* p = ws + off; off = (off + bytes + 255) & ~(size_t)255; return p; };
  unsigned short* Xh = (unsigned short*)alloc((size_t)SEG_X * 2);
  unsigned short* Xc = (unsigned short*)alloc((size_t)SEG_X * 2);
  unsigned short* Wa = (unsigned short*)alloc((size_t)3 * SEG_W1 * 2);
  float*          Ba = (float*)alloc((size_t)NTOT * 4);
  unsigned short* qw = (unsigned short*)alloc((size_t)BH_ * SQ_ * DH_ * 2);
  unsigned short* kw = (unsigned short*)alloc((size_t)BH_ * SK_ * DH_ * 2);
  unsigned short* vt = (unsigned short*)alloc((size_t)BH_ * DH_ * SK_ * 2);
  unsigned short* Pb = (unsigned short*)alloc((size_t)SQ_ * DH_ * 2);

  int pack_blocks = (SEG_PE / 4 + 255) / 256;
  pack_kernel<<<pack_blocks, 256, 0, stream>>>(hid, ctx, Wq, Wk, Wv, bq, bk, bv, pos, Xh, Xc, Wa, Ba, Pb);
  qkv_gemm<<<32 * 18, 256, 0, stream>>>(Xh, Xc, Wa, Ba, pos, qw, kw, vt);
  attn_kernel<<<BH_ * 16, 256, 0, stream>>>(qw, kw, vt, Pb, mask, (float*)d_out);
}

// Round 3
// 190.130 us; speedup vs baseline: 1.0942x; 1.0658x over previous
//
#include <hip/hip_runtime.h>
#include <stdint.h>

// ---- problem constants ----
#define B_   8
#define SQ_  512
#define SK_  512
#define H_   768
#define NH_  12
#define DH_  64
#define BH_  (B_*NH_)          // 96 (b,h) pairs
#define M_   (B_*SQ_)          // 4096 rows for both hidden and context
#define NTOT (3*H_)            // 2304 fused QKV output columns

typedef __attribute__((ext_vector_type(8))) short short8;
typedef __attribute__((ext_vector_type(4))) float floatx4;
typedef __attribute__((ext_vector_type(4))) unsigned int uint4v;
typedef __attribute__((ext_vector_type(4))) unsigned short ushort4v;

#define MFMA16(a, b, c) __builtin_amdgcn_mfma_f32_16x16x32_bf16((a), (b), (c), 0, 0, 0)

__device__ __forceinline__ unsigned short f2b(float f) {   // fp32 -> bf16 bits (RNE)
  union { float f; unsigned u; } c; c.f = f;
  unsigned r = (c.u + 0x7fffu + ((c.u >> 16) & 1u)) >> 16;
  return (unsigned short)r;
}
__device__ __forceinline__ float b2f(unsigned short u) {   // bf16 bits -> fp32
  union { float f; unsigned u; } c; c.u = ((unsigned)u) << 16;
  return c.f;
}
__device__ __forceinline__ unsigned short f2h(float f) {   // fp32 -> fp16 bits
  union { _Float16 h; unsigned short u; } c; c.h = (_Float16)f;
  return c.u;
}
__device__ __forceinline__ float h2f(unsigned short u) {
  union { _Float16 h; unsigned short u; } c; c.u = u;
  return (float)c.h;
}
__device__ __forceinline__ short8 ld8(const unsigned short* p) {  // 16B vector load
  union { uint4v u; short8 s; } c;
  c.u = *(const uint4v*)p;
  return c.s;
}
__device__ __forceinline__ void st8(unsigned short* p, short8 v) {
  union { uint4v u; short8 s; } c; c.s = v;
  *(uint4v*)p = c.u;
}

// ---------------------------------------------------------------------------
// Kernel 1: pack fp32 inputs -> bf16 workspace (hidden, context, W, pos, biases)
// ---------------------------------------------------------------------------
#define SEG_X   (M_*H_)          // 3145728 (hidden)
#define SEG_XC  (2*SEG_X)        // 6291456 (end of context)
#define SEG_W1  (H_*H_)          // 589824
#define SEG_WE  (SEG_XC + 3*SEG_W1)   // 8060928
#define SEG_BE  (SEG_WE + NTOT)  // 8063232
#define SEG_PE  (SEG_BE + SQ_*DH_)    // 8096000 (pos bf16)

__global__ __launch_bounds__(256) void pack_kernel(
    const float* __restrict__ hid, const float* __restrict__ ctx,
    const float* __restrict__ Wq, const float* __restrict__ Wk, const float* __restrict__ Wv,
    const float* __restrict__ bq, const float* __restrict__ bk, const float* __restrict__ bv,
    const float* __restrict__ pos,
    unsigned short* __restrict__ Xh, unsigned short* __restrict__ Xc,
    unsigned short* __restrict__ Wa, float* __restrict__ Ba,
    unsigned short* __restrict__ Pb)
{
  int i = (blockIdx.x * 256 + threadIdx.x) * 4;
  if (i < SEG_X) {
    floatx4 v = *(const floatx4*)(hid + i);
    ushort4v o = { f2b(v.x), f2b(v.y), f2b(v.z), f2b(v.w) };
    *(ushort4v*)(Xh + i) = o;
  } else if (i < SEG_XC) {
    int j = i - SEG_X;
    floatx4 v = *(const floatx4*)(ctx + j);
    ushort4v o = { f2b(v.x), f2b(v.y), f2b(v.z), f2b(v.w) };
    *(ushort4v*)(Xc + j) = o;
  } else if (i < SEG_WE) {
    int j = i - SEG_XC;
    const float* src; int o;
    if (j < SEG_W1)        { src = Wq; o = j; }
    else if (j < 2*SEG_W1) { src = Wk; o = j - SEG_W1; }
    else                   { src = Wv; o = j - 2*SEG_W1; }
    floatx4 v = *(const floatx4*)(src + o);
    ushort4v ov = { f2b(v.x), f2b(v.y), f2b(v.z), f2b(v.w) };
    *(ushort4v*)(Wa + j) = ov;
  } else if (i < SEG_BE) {
    int j = i - SEG_WE;
    #pragma unroll
    for (int t = 0; t < 4; ++t) {
      int jj = j + t;
      float v = (jj < H_) ? bq[jj] : (jj < 2*H_) ? bk[jj - H_] : bv[jj - 2*H_];
      Ba[jj] = v;
    }
  } else if (i < SEG_PE) {
    int j = i - SEG_BE;
    floatx4 v = *(const floatx4*)(pos + j);
    ushort4v o = { f2b(v.x), f2b(v.y), f2b(v.z), f2b(v.w) };
    *(ushort4v*)(Pb + j) = o;
  }
}

// ---------------------------------------------------------------------------
// Kernel 2: fused QKV projection GEMM (bf16 MFMA), M=4096 x N=2304 x K=768
//   C = X @ W^T + b ; epilogue scatters into head layouts:
//     Q  -> qw[bh][s][d]  (bf16)
//     K  -> kw[bh][s][d] = k + pos_emb[s][d]  (bf16)   [folds pos_k]
//     V  -> vt[bh][d][s]  (bf16, transposed for PV B-operand)
// For Q/K tiles the MFMA operand roles are swapped (A=W rows, B=X rows) so
// each lane's 4 D-values are 4 consecutive FEATURES -> 8B vector stores along d.
// For V tiles normal orientation -> 8B vector stores along s (vt layout).
// ---------------------------------------------------------------------------
__global__ __launch_bounds__(256) void qkv_gemm(
    const unsigned short* __restrict__ Xh, const unsigned short* __restrict__ Xc,
    const unsigned short* __restrict__ W,  const float* __restrict__ bias,
    const unsigned short* __restrict__ Pb,
    unsigned short* __restrict__ qw, unsigned short* __restrict__ kw,
    unsigned short* __restrict__ vt)
{
  __shared__ unsigned short As[128][72];
  __shared__ unsigned short Bs[128][72];

  int bx = blockIdx.x;
  int bn = bx % 18, bm = bx / 18;          // 18 n-tiles, 32 m-tiles
  const unsigned short* X = (bn < 6) ? Xh : Xc;
  bool isV = (bn >= 12);
  int m0 = bm * 128, n0 = bn * 128;

  int tid = threadIdx.x;
  int lane = tid & 63, wave = tid >> 6;
  int wm = (wave & 1) * 64, wn = (wave >> 1) * 64;
  int lc16 = lane & 15, quad = lane >> 4, kk = quad * 8;
  int srow = tid >> 3, sch = (tid & 7) * 8;   // staging: 32 rows x 8 chunks of 8

  // operand-source swap: A-operand tile / B-operand tile
  unsigned short (*TA)[72] = isV ? As : Bs;
  unsigned short (*TB)[72] = isV ? Bs : As;
  int oa = isV ? wm : wn;
  int ob = isV ? wn : wm;

  floatx4 acc[4][4];
  #pragma unroll
  for (int i = 0; i < 4; ++i)
    #pragma unroll
    for (int j = 0; j < 4; ++j) acc[i][j] = (floatx4){0.f, 0.f, 0.f, 0.f};

  for (int k0 = 0; k0 < H_; k0 += 64) {
    uint4v a[4], b[4];
    #pragma unroll
    for (int rp = 0; rp < 4; ++rp) {
      a[rp] = *(const uint4v*)&X[(m0 + srow + rp * 32) * H_ + k0 + sch];
      b[rp] = *(const uint4v*)&W[(n0 + srow + rp * 32) * H_ + k0 + sch];
    }
    __syncthreads();
    #pragma unroll
    for (int rp = 0; rp < 4; ++rp) {
      *(uint4v*)&As[srow + rp * 32][sch] = a[rp];
      *(uint4v*)&Bs[srow + rp * 32][sch] = b[rp];
    }
    __syncthreads();

    #pragma unroll
    for (int s = 0; s < 2; ++s) {
      short8 af[4], bf[4];
      #pragma unroll
      for (int i = 0; i < 4; ++i) af[i] = ld8(&TA[oa + i * 16 + lc16][s * 32 + kk]);
      #pragma unroll
      for (int i = 0; i < 4; ++i) bf[i] = ld8(&TB[ob + i * 16 + lc16][s * 32 + kk]);
      #pragma unroll
      for (int mi = 0; mi < 4; ++mi)
        #pragma unroll
        for (int ni = 0; ni < 4; ++ni)
          acc[mi][ni] = MFMA16(af[mi], bf[ni], acc[mi][ni]);
    }
  }

  if (!isV) {
    // D row (quad*4+r) = feature n, D col (lc16) = sequence m
    #pragma unroll
    for (int mi = 0; mi < 4; ++mi) {
      #pragma unroll
      for (int ni = 0; ni < 4; ++ni) {
        int gn0 = n0 + wn + mi * 16 + quad * 4;     // 4 consecutive features
        int gs  = m0 + wm + ni * 16 + lc16;         // sequence index
        int bidx = gs >> 9, s0 = gs & 511;
        floatx4 bv4 = *(const floatx4*)&bias[gn0];
        ushort4v o;
        if (gn0 < H_) {                              // Q
          int h = gn0 >> 6, d0 = gn0 & 63;
          #pragma unroll
          for (int r = 0; r < 4; ++r) o[r] = f2b(acc[mi][ni][r] + bv4[r]);
          *(ushort4v*)(qw + (((bidx * NH_ + h) << 9) + s0) * DH_ + d0) = o;
        } else {                                     // K (+ bf16 pos_k)
          int g = gn0 - H_;
          int h = g >> 6, d0 = g & 63;
          ushort4v pk = *(const ushort4v*)(Pb + s0 * DH_ + d0);
          #pragma unroll
          for (int r = 0; r < 4; ++r) o[r] = f2b(acc[mi][ni][r] + bv4[r] + b2f(pk[r]));
          *(ushort4v*)(kw + (((bidx * NH_ + h) << 9) + s0) * DH_ + d0) = o;
        }
      }
    }
  } else {
    // D row = sequence m (4 consecutive s), D col = feature n
    #pragma unroll
    for (int mi = 0; mi < 4; ++mi) {
      #pragma unroll
      for (int ni = 0; ni < 4; ++ni) {
        int gm0 = m0 + wm + mi * 16 + quad * 4;
        int gn  = n0 + wn + ni * 16 + lc16;
        float bv = bias[gn];
        int bidx = gm0 >> 9, s0 = gm0 & 511;
        int g = gn - 2 * H_;
        int h = g >> 6, d = g & 63;
        ushort4v pk;
        #pragma unroll
        for (int r = 0; r < 4; ++r) pk[r] = f2b(acc[mi][ni][r] + bv);
        *(ushort4v*)(vt + ((bidx * NH_ + h) * DH_ + d) * SK_ + s0) = pk;
      }
    }
  }
}

// ---------------------------------------------------------------------------
// Kernel 3: attention. 1 block = one (b,h) x 64 q-rows. 4 waves.
//   scores = (q @ (k+pos_k)^T + pos_q @ pos_k^T) / 8 + maskbias   (all MFMA)
//   QK: each wave owns ALL 64 q-rows (16 A-frags in regs) and a 128-col slice
//       -> per 16-col tile: 4 B-loads, 16 MFMAs in 4 independent chains.
//   -> fp16 S in LDS -> softmax -> bf16 probs in-place -> PV (waves split d).
// ---------------------------------------------------------------------------
#define SPAD 524   // row stride in shorts: 262 words == 6 mod 32 -> 16-bank spread

__global__ __launch_bounds__(256) void attn_kernel(
    const unsigned short* __restrict__ qw, const unsigned short* __restrict__ kw,
    const unsigned short* __restrict__ vt, const unsigned short* __restrict__ posb,
    const int* __restrict__ mask, float* __restrict__ out)
{
  __shared__ unsigned short S[64][SPAD];   // fp16 logits, then bf16 probs
  __shared__ float mb[SK_];
  __shared__ float red[64][4];
  __shared__ float rsum[64];

  int bx = blockIdx.x;
  int bh = bx >> 3, qt = bx & 7;           // 8 q-tiles of 64 rows
  int b = bh / NH_, h = bh - b * NH_;
  int tid = threadIdx.x, lane = tid & 63, wave = tid >> 6;
  int lc16 = lane & 15, quad = lane >> 4, kk = quad * 8;

  for (int i = tid; i < SK_; i += 256)
    mb[i] = mask[(b << 9) + i] ? 0.0f : -30000.0f;

  // A-frags: 4 row-tiles x (2 q + 2 pos_q) K-fragments, held in regs all phase
  const unsigned short* qbase = qw + ((bh << 9) + qt * 64) * DH_;
  const unsigned short* pqb   = posb + (qt * 64) * DH_;
  short8 aq[4][2], ap[4][2];
  #pragma unroll
  for (int rt = 0; rt < 4; ++rt) {
    const unsigned short* qr = qbase + (rt * 16 + lc16) * DH_;
    const unsigned short* pr = pqb + (rt * 16 + lc16) * DH_;
    aq[rt][0] = ld8(qr + kk);
    aq[rt][1] = ld8(qr + 32 + kk);
    ap[rt][0] = ld8(pr + kk);
    ap[rt][1] = ld8(pr + 32 + kk);
  }
  __syncthreads();   // mask bias ready

  // QK phase: wave owns cols [wave*128, wave*128+128)
  int w0 = wave * 128;
  #pragma unroll 2
  for (int ct = 0; ct < 8; ++ct) {
    int kcol = w0 + ct * 16;
    const unsigned short* kb = kw + ((bh << 9) + kcol) * DH_;
    const unsigned short* pb = posb + kcol * DH_;
    short8 b0 = ld8(kb + lc16 * DH_ + kk);
    short8 b1 = ld8(kb + lc16 * DH_ + 32 + kk);
    short8 p0 = ld8(pb + lc16 * DH_ + kk);
    short8 p1 = ld8(pb + lc16 * DH_ + 32 + kk);
    float mbias = mb[kcol + lc16];
    floatx4 c[4];
    #pragma unroll
    for (int rt = 0; rt < 4; ++rt) {
      c[rt] = (floatx4){0.f, 0.f, 0.f, 0.f};
      c[rt] = MFMA16(aq[rt][0], b0, c[rt]);
      c[rt] = MFMA16(aq[rt][1], b1, c[rt]);
      c[rt] = MFMA16(ap[rt][0], p0, c[rt]);
      c[rt] = MFMA16(ap[rt][1], p1, c[rt]);
    }
    #pragma unroll
    for (int rt = 0; rt < 4; ++rt)
      #pragma unroll
      for (int r = 0; r < 4; ++r)
        S[rt * 16 + quad * 4 + r][kcol + lc16] = f2h(c[rt][r] * 0.125f + mbias);
  }
  __syncthreads();

  // softmax: 4 threads per row, 128 elems each
  int row = tid >> 2, part = tid & 3;
  unsigned short* Sr = &S[row][part * 128];
  float mx = -3.0e38f;
  #pragma unroll
  for (int i = 0; i < 16; ++i) {
    short8 v = ld8(Sr + 8 * i);
    #pragma unroll
    for (int j = 0; j < 8; ++j) mx = fmaxf(mx, h2f((unsigned short)v[j]));
  }
  red[row][part] = mx;
  __syncthreads();
  mx = fmaxf(fmaxf(red[row][0], red[row][1]), fmaxf(red[row][2], red[row][3]));
  __syncthreads();
  float sm = 0.f;
  #pragma unroll
  for (int i = 0; i < 16; ++i) {
    short8 v = ld8(Sr + 8 * i);
    short8 o;
    #pragma unroll
    for (int j = 0; j < 8; ++j) {
      float e = __expf(h2f((unsigned short)v[j]) - mx);
      sm += e;
      o[j] = (short)f2b(e);            // unnormalized prob in [0,1]
    }
    st8(Sr + 8 * i, o);
  }
  red[row][part] = sm;
  __syncthreads();
  if (part == 0)
    rsum[row] = red[row][0] + red[row][1] + red[row][2] + red[row][3];
  __syncthreads();

  // PV: wave owns d-slice [wave*16, wave*16+16); all 64 q-rows; K=512
  const unsigned short* vb0 = vt + (bh * DH_ + wave * 16 + lc16) * SK_;
  floatx4 o[4];
  #pragma unroll
  for (int i = 0; i < 4; ++i) o[i] = (floatx4){0.f, 0.f, 0.f, 0.f};
  #pragma unroll 2
  for (int ks = 0; ks < 16; ++ks) {
    short8 vf = ld8(vb0 + ks * 32 + kk);
    #pragma unroll
    for (int rt = 0; rt < 4; ++rt) {
      short8 pa = ld8(&S[rt * 16 + lc16][ks * 32 + kk]);
      o[rt] = MFMA16(pa, vf, o[rt]);
    }
  }

  #pragma unroll
  for (int rt = 0; rt < 4; ++rt) {
    #pragma unroll
    for (int r = 0; r < 4; ++r) {
      int sl = rt * 16 + quad * 4 + r;
      int s = qt * 64 + sl;
      out[((b << 9) + s) * H_ + h * DH_ + wave * 16 + lc16] = o[rt][r] / rsum[sl];
    }
  }
}

// ---------------------------------------------------------------------------
// host launcher
// ---------------------------------------------------------------------------
extern "C" void kernel_launch(void* const* d_in, const int* in_sizes, int n_in,
                              void* d_out, int out_size, void* d_ws, size_t ws_size,
                              hipStream_t stream) {
  (void)in_sizes; (void)n_in; (void)out_size; (void)ws_size;
  const float* hid  = (const float*)d_in[0];
  const float* ctx  = (const float*)d_in[1];
  const int*   mask = (const int*)d_in[2];
  const float* Wq   = (const float*)d_in[3];
  const float* bq   = (const float*)d_in[4];
  const float* Wk   = (const float*)d_in[5];
  const float* bk   = (const float*)d_in[6];
  const float* Wv   = (const float*)d_in[7];
  const float* bv   = (const float*)d_in[8];
  const float* pos  = (const float*)d_in[9];

  char* ws = (char*)d_ws;
  size_t off = 0;
  auto alloc = [&](size_t bytes) { char* p = ws + off; off = (off + bytes + 255) & ~(size_t)255; return p; };
  unsigned short* Xh = (unsigned short*)alloc((size_t)SEG_X * 2);
  unsigned short* Xc = (unsigned short*)alloc((size_t)SEG_X * 2);
  unsigned short* Wa = (unsigned short*)alloc((size_t)3 * SEG_W1 * 2);
  float*          Ba = (float*)alloc((size_t)NTOT * 4);
  unsigned short* qw = (unsigned short*)alloc((size_t)BH_ * SQ_ * DH_ * 2);
  unsigned short* kw = (unsigned short*)alloc((size_t)BH_ * SK_ * DH_ * 2);
  unsigned short* vt = (unsigned short*)alloc((size_t)BH_ * DH_ * SK_ * 2);
  unsigned short* Pb = (unsigned short*)alloc((size_t)SQ_ * DH_ * 2);

  int pack_blocks = (SEG_PE / 4 + 255) / 256;
  pack_kernel<<<pack_blocks, 256, 0, stream>>>(hid, ctx, Wq, Wk, Wv, bq, bk, bv, pos, Xh, Xc, Wa, Ba, Pb);
  qkv_gemm<<<32 * 18, 256, 0, stream>>>(Xh, Xc, Wa, Ba, Pb, qw, kw, vt);
  attn_kernel<<<BH_ * 8, 256, 0, stream>>>(qw, kw, vt, Pb, mask, (float*)d_out);
}

// Round 4
// 173.813 us; speedup vs baseline: 1.1969x; 1.0939x over previous
//
#include <hip/hip_runtime.h>
#include <stdint.h>

// ---- problem constants ----
#define B_   8
#define SQ_  512
#define SK_  512
#define H_   768
#define NH_  12
#define DH_  64
#define BH_  (B_*NH_)          // 96 (b,h) pairs
#define M_   (B_*SQ_)          // 4096 rows for both hidden and context
#define NTOT (3*H_)            // 2304 fused QKV output columns

typedef __attribute__((ext_vector_type(8))) short short8;
typedef __attribute__((ext_vector_type(4))) float floatx4;
typedef __attribute__((ext_vector_type(4))) unsigned int uint4v;
typedef __attribute__((ext_vector_type(4))) unsigned short ushort4v;

#define MFMA16(a, b, c) __builtin_amdgcn_mfma_f32_16x16x32_bf16((a), (b), (c), 0, 0, 0)

__device__ __forceinline__ unsigned short f2b(float f) {   // fp32 -> bf16 bits (RNE)
  union { float f; unsigned u; } c; c.f = f;
  unsigned r = (c.u + 0x7fffu + ((c.u >> 16) & 1u)) >> 16;
  return (unsigned short)r;
}
__device__ __forceinline__ float b2f(unsigned short u) {   // bf16 bits -> fp32
  union { float f; unsigned u; } c; c.u = ((unsigned)u) << 16;
  return c.f;
}
__device__ __forceinline__ short8 ld8(const unsigned short* p) {  // 16B vector load
  union { uint4v u; short8 s; } c;
  c.u = *(const uint4v*)p;
  return c.s;
}

// ---------------------------------------------------------------------------
// Kernel 1: pack fp32 inputs -> bf16 workspace (hidden, context, W, pos, biases)
// ---------------------------------------------------------------------------
#define SEG_X   (M_*H_)          // 3145728 (hidden)
#define SEG_XC  (2*SEG_X)        // 6291456 (end of context)
#define SEG_W1  (H_*H_)          // 589824
#define SEG_WE  (SEG_XC + 3*SEG_W1)   // 8060928
#define SEG_BE  (SEG_WE + NTOT)  // 8063232
#define SEG_PE  (SEG_BE + SQ_*DH_)    // 8096000 (pos bf16)

__global__ __launch_bounds__(256) void pack_kernel(
    const float* __restrict__ hid, const float* __restrict__ ctx,
    const float* __restrict__ Wq, const float* __restrict__ Wk, const float* __restrict__ Wv,
    const float* __restrict__ bq, const float* __restrict__ bk, const float* __restrict__ bv,
    const float* __restrict__ pos,
    unsigned short* __restrict__ Xh, unsigned short* __restrict__ Xc,
    unsigned short* __restrict__ Wa, float* __restrict__ Ba,
    unsigned short* __restrict__ Pb)
{
  int i = (blockIdx.x * 256 + threadIdx.x) * 4;
  if (i < SEG_X) {
    floatx4 v = *(const floatx4*)(hid + i);
    ushort4v o = { f2b(v.x), f2b(v.y), f2b(v.z), f2b(v.w) };
    *(ushort4v*)(Xh + i) = o;
  } else if (i < SEG_XC) {
    int j = i - SEG_X;
    floatx4 v = *(const floatx4*)(ctx + j);
    ushort4v o = { f2b(v.x), f2b(v.y), f2b(v.z), f2b(v.w) };
    *(ushort4v*)(Xc + j) = o;
  } else if (i < SEG_WE) {
    int j = i - SEG_XC;
    const float* src; int o;
    if (j < SEG_W1)        { src = Wq; o = j; }
    else if (j < 2*SEG_W1) { src = Wk; o = j - SEG_W1; }
    else                   { src = Wv; o = j - 2*SEG_W1; }
    floatx4 v = *(const floatx4*)(src + o);
    ushort4v ov = { f2b(v.x), f2b(v.y), f2b(v.z), f2b(v.w) };
    *(ushort4v*)(Wa + j) = ov;
  } else if (i < SEG_BE) {
    int j = i - SEG_WE;
    #pragma unroll
    for (int t = 0; t < 4; ++t) {
      int jj = j + t;
      float v = (jj < H_) ? bq[jj] : (jj < 2*H_) ? bk[jj - H_] : bv[jj - 2*H_];
      Ba[jj] = v;
    }
  } else if (i < SEG_PE) {
    int j = i - SEG_BE;
    floatx4 v = *(const floatx4*)(pos + j);
    ushort4v o = { f2b(v.x), f2b(v.y), f2b(v.z), f2b(v.w) };
    *(ushort4v*)(Pb + j) = o;
  }
}

// ---------------------------------------------------------------------------
// Kernel 2: fused QKV projection GEMM (bf16 MFMA), M=4096 x N=2304 x K=768
//   (unchanged from round 3)
// ---------------------------------------------------------------------------
__global__ __launch_bounds__(256) void qkv_gemm(
    const unsigned short* __restrict__ Xh, const unsigned short* __restrict__ Xc,
    const unsigned short* __restrict__ W,  const float* __restrict__ bias,
    const unsigned short* __restrict__ Pb,
    unsigned short* __restrict__ qw, unsigned short* __restrict__ kw,
    unsigned short* __restrict__ vt)
{
  __shared__ unsigned short As[128][72];
  __shared__ unsigned short Bs[128][72];

  int bx = blockIdx.x;
  int bn = bx % 18, bm = bx / 18;          // 18 n-tiles, 32 m-tiles
  const unsigned short* X = (bn < 6) ? Xh : Xc;
  bool isV = (bn >= 12);
  int m0 = bm * 128, n0 = bn * 128;

  int tid = threadIdx.x;
  int lane = tid & 63, wave = tid >> 6;
  int wm = (wave & 1) * 64, wn = (wave >> 1) * 64;
  int lc16 = lane & 15, quad = lane >> 4, kk = quad * 8;
  int srow = tid >> 3, sch = (tid & 7) * 8;   // staging: 32 rows x 8 chunks of 8

  unsigned short (*TA)[72] = isV ? As : Bs;
  unsigned short (*TB)[72] = isV ? Bs : As;
  int oa = isV ? wm : wn;
  int ob = isV ? wn : wm;

  floatx4 acc[4][4];
  #pragma unroll
  for (int i = 0; i < 4; ++i)
    #pragma unroll
    for (int j = 0; j < 4; ++j) acc[i][j] = (floatx4){0.f, 0.f, 0.f, 0.f};

  for (int k0 = 0; k0 < H_; k0 += 64) {
    uint4v a[4], b[4];
    #pragma unroll
    for (int rp = 0; rp < 4; ++rp) {
      a[rp] = *(const uint4v*)&X[(m0 + srow + rp * 32) * H_ + k0 + sch];
      b[rp] = *(const uint4v*)&W[(n0 + srow + rp * 32) * H_ + k0 + sch];
    }
    __syncthreads();
    #pragma unroll
    for (int rp = 0; rp < 4; ++rp) {
      *(uint4v*)&As[srow + rp * 32][sch] = a[rp];
      *(uint4v*)&Bs[srow + rp * 32][sch] = b[rp];
    }
    __syncthreads();

    #pragma unroll
    for (int s = 0; s < 2; ++s) {
      short8 af[4], bf[4];
      #pragma unroll
      for (int i = 0; i < 4; ++i) af[i] = ld8(&TA[oa + i * 16 + lc16][s * 32 + kk]);
      #pragma unroll
      for (int i = 0; i < 4; ++i) bf[i] = ld8(&TB[ob + i * 16 + lc16][s * 32 + kk]);
      #pragma unroll
      for (int mi = 0; mi < 4; ++mi)
        #pragma unroll
        for (int ni = 0; ni < 4; ++ni)
          acc[mi][ni] = MFMA16(af[mi], bf[ni], acc[mi][ni]);
    }
  }

  if (!isV) {
    #pragma unroll
    for (int mi = 0; mi < 4; ++mi) {
      #pragma unroll
      for (int ni = 0; ni < 4; ++ni) {
        int gn0 = n0 + wn + mi * 16 + quad * 4;     // 4 consecutive features
        int gs  = m0 + wm + ni * 16 + lc16;         // sequence index
        int bidx = gs >> 9, s0 = gs & 511;
        floatx4 bv4 = *(const floatx4*)&bias[gn0];
        ushort4v o;
        if (gn0 < H_) {                              // Q
          int h = gn0 >> 6, d0 = gn0 & 63;
          #pragma unroll
          for (int r = 0; r < 4; ++r) o[r] = f2b(acc[mi][ni][r] + bv4[r]);
          *(ushort4v*)(qw + (((bidx * NH_ + h) << 9) + s0) * DH_ + d0) = o;
        } else {                                     // K (+ bf16 pos_k)
          int g = gn0 - H_;
          int h = g >> 6, d0 = g & 63;
          ushort4v pk = *(const ushort4v*)(Pb + s0 * DH_ + d0);
          #pragma unroll
          for (int r = 0; r < 4; ++r) o[r] = f2b(acc[mi][ni][r] + bv4[r] + b2f(pk[r]));
          *(ushort4v*)(kw + (((bidx * NH_ + h) << 9) + s0) * DH_ + d0) = o;
        }
      }
    }
  } else {
    #pragma unroll
    for (int mi = 0; mi < 4; ++mi) {
      #pragma unroll
      for (int ni = 0; ni < 4; ++ni) {
        int gm0 = m0 + wm + mi * 16 + quad * 4;
        int gn  = n0 + wn + ni * 16 + lc16;
        float bv = bias[gn];
        int bidx = gm0 >> 9, s0 = gm0 & 511;
        int g = gn - 2 * H_;
        int h = g >> 6, d = g & 63;
        ushort4v pk;
        #pragma unroll
        for (int r = 0; r < 4; ++r) pk[r] = f2b(acc[mi][ni][r] + bv);
        *(ushort4v*)(vt + ((bidx * NH_ + h) * DH_ + d) * SK_ + s0) = pk;
      }
    }
  }
}

// ---------------------------------------------------------------------------
// Kernel 3: attention, softmax fused into QK epilogue (no max pass).
//   1 block = one (b,h) x 64 q-rows; k processed in 4 chunks of 128.
//   QK (A=K-tile, B=Q-rows): D gives 4 consecutive k per lane at fixed q-row
//   -> p = exp2(score*log2e/8 + maskbias2) -> bf16 -> 8B LDS store + per-lane
//   running row-sum. PV per chunk accumulates O in regs. No rescaling needed.
// ---------------------------------------------------------------------------
#define SCALE2 0.18033688011112042f   // (1/8) * log2(e)
#define CPAD 136                      // chunk row stride (128 + 8)

__global__ __launch_bounds__(256) void attn_kernel(
    const unsigned short* __restrict__ qw, const unsigned short* __restrict__ kw,
    const unsigned short* __restrict__ vt, const unsigned short* __restrict__ posb,
    const int* __restrict__ mask, float* __restrict__ out)
{
  __shared__ unsigned short Sc[64][CPAD];   // bf16 probs, one 128-col chunk
  __shared__ float mb2[SK_];                // mask bias in exp2 domain
  __shared__ float red[64][4];              // per-wave row-sum partials

  int bx = blockIdx.x;
  int bh = bx >> 3, qt = bx & 7;           // 8 q-tiles of 64 rows
  int b = bh / NH_, h = bh - b * NH_;
  int tid = threadIdx.x, lane = tid & 63, wave = tid >> 6;
  int lc16 = lane & 15, quad = lane >> 4, kk = quad * 8;

  for (int i = tid; i < SK_; i += 256)
    mb2[i] = mask[(b << 9) + i] ? 0.0f : -100000.0f;

  // B-frags (held all QK phases): 4 row-tiles x (2 q + 2 pos_q) K-fragments
  const unsigned short* qbase = qw + ((bh << 9) + qt * 64) * DH_;
  const unsigned short* pqb   = posb + (qt * 64) * DH_;
  short8 aq[4][2], ap[4][2];
  #pragma unroll
  for (int rt = 0; rt < 4; ++rt) {
    const unsigned short* qr = qbase + (rt * 16 + lc16) * DH_;
    const unsigned short* pr = pqb + (rt * 16 + lc16) * DH_;
    aq[rt][0] = ld8(qr + kk);
    aq[rt][1] = ld8(qr + 32 + kk);
    ap[rt][0] = ld8(pr + kk);
    ap[rt][1] = ld8(pr + 32 + kk);
  }

  const unsigned short* vb0 = vt + (bh * DH_ + wave * 16 + lc16) * SK_;
  float rs[4] = {0.f, 0.f, 0.f, 0.f};      // per-lane row-sum partials (row rt*16+lc16)
  floatx4 o[4];
  #pragma unroll
  for (int i = 0; i < 4; ++i) o[i] = (floatx4){0.f, 0.f, 0.f, 0.f};

  __syncthreads();   // mb2 ready

  for (int chunk = 0; chunk < 4; ++chunk) {
    // ---- QK + exp: wave owns chunk-local cols [wave*32, wave*32+32) ----
    #pragma unroll
    for (int ct = 0; ct < 2; ++ct) {
      int kcol = chunk * 128 + wave * 32 + ct * 16;
      const unsigned short* kb = kw + ((bh << 9) + kcol) * DH_;
      const unsigned short* pb = posb + kcol * DH_;
      short8 b0 = ld8(kb + lc16 * DH_ + kk);
      short8 b1 = ld8(kb + lc16 * DH_ + 32 + kk);
      short8 p0 = ld8(pb + lc16 * DH_ + kk);
      short8 p1 = ld8(pb + lc16 * DH_ + 32 + kk);
      floatx4 mk = *(const floatx4*)&mb2[kcol + quad * 4];
      floatx4 c[4];
      #pragma unroll
      for (int rt = 0; rt < 4; ++rt) {
        c[rt] = (floatx4){0.f, 0.f, 0.f, 0.f};
        c[rt] = MFMA16(b0, aq[rt][0], c[rt]);   // A=K-tile, B=Q-rows
        c[rt] = MFMA16(b1, aq[rt][1], c[rt]);
        c[rt] = MFMA16(p0, ap[rt][0], c[rt]);
        c[rt] = MFMA16(p1, ap[rt][1], c[rt]);
      }
      int lcol = wave * 32 + ct * 16 + quad * 4;   // chunk-local col base
      #pragma unroll
      for (int rt = 0; rt < 4; ++rt) {
        ushort4v pv;
        float s = 0.f;
        #pragma unroll
        for (int r = 0; r < 4; ++r) {
          float e = __builtin_exp2f(c[rt][r] * SCALE2 + mk[r]);
          s += e;
          pv[r] = f2b(e);
        }
        rs[rt] += s;
        *(ushort4v*)&Sc[rt * 16 + lc16][lcol] = pv;
      }
    }
    __syncthreads();   // probs chunk ready

    // ---- PV over this chunk: wave owns d-slice [wave*16, +16) ----
    #pragma unroll
    for (int ks = 0; ks < 4; ++ks) {
      short8 vf = ld8(vb0 + chunk * 128 + ks * 32 + kk);
      #pragma unroll
      for (int rt = 0; rt < 4; ++rt) {
        short8 pa = ld8(&Sc[rt * 16 + lc16][ks * 32 + kk]);
        o[rt] = MFMA16(pa, vf, o[rt]);
      }
    }
    __syncthreads();   // chunk consumed before overwrite
  }

  // ---- row-sum: reduce across quads, then across waves via LDS ----
  #pragma unroll
  for (int rt = 0; rt < 4; ++rt) {
    rs[rt] += __shfl_xor(rs[rt], 16, 64);
    rs[rt] += __shfl_xor(rs[rt], 32, 64);
  }
  if (quad == 0) {
    #pragma unroll
    for (int rt = 0; rt < 4; ++rt) red[rt * 16 + lc16][wave] = rs[rt];
  }
  __syncthreads();

  #pragma unroll
  for (int rt = 0; rt < 4; ++rt) {
    #pragma unroll
    for (int r = 0; r < 4; ++r) {
      int sl = rt * 16 + quad * 4 + r;
      float inv = 1.0f / (red[sl][0] + red[sl][1] + red[sl][2] + red[sl][3]);
      int s = qt * 64 + sl;
      out[((b << 9) + s) * H_ + h * DH_ + wave * 16 + lc16] = o[rt][r] * inv;
    }
  }
}

// ---------------------------------------------------------------------------
// host launcher
// ---------------------------------------------------------------------------
extern "C" void kernel_launch(void* const* d_in, const int* in_sizes, int n_in,
                              void* d_out, int out_size, void* d_ws, size_t ws_size,
                              hipStream_t stream) {
  (void)in_sizes; (void)n_in; (void)out_size; (void)ws_size;
  const float* hid  = (const float*)d_in[0];
  const float* ctx  = (const float*)d_in[1];
  const int*   mask = (const int*)d_in[2];
  const float* Wq   = (const float*)d_in[3];
  const float* bq   = (const float*)d_in[4];
  const float* Wk   = (const float*)d_in[5];
  const float* bk   = (const float*)d_in[6];
  const float* Wv   = (const float*)d_in[7];
  const float* bv   = (const float*)d_in[8];
  const float* pos  = (const float*)d_in[9];

  char* ws = (char*)d_ws;
  size_t off = 0;
  auto alloc = [&](size_t bytes) { char* p = ws + off; off = (off + bytes + 255) & ~(size_t)255; return p; };
  unsigned short* Xh = (unsigned short*)alloc((size_t)SEG_X * 2);
  unsigned short* Xc = (unsigned short*)alloc((size_t)SEG_X * 2);
  unsigned short* Wa = (unsigned short*)alloc((size_t)3 * SEG_W1 * 2);
  float*          Ba = (float*)alloc((size_t)NTOT * 4);
  unsigned short* qw = (unsigned short*)alloc((size_t)BH_ * SQ_ * DH_ * 2);
  unsigned short* kw = (unsigned short*)alloc((size_t)BH_ * SK_ * DH_ * 2);
  unsigned short* vt = (unsigned short*)alloc((size_t)BH_ * DH_ * SK_ * 2);
  unsigned short* Pb = (unsigned short*)alloc((size_t)SQ_ * DH_ * 2);

  int pack_blocks = (SEG_PE / 4 + 255) / 256;
  pack_kernel<<<pack_blocks, 256, 0, stream>>>(hid, ctx, Wq, Wk, Wv, bq, bk, bv, pos, Xh, Xc, Wa, Ba, Pb);
  qkv_gemm<<<32 * 18, 256, 0, stream>>>(Xh, Xc, Wa, Ba, Pb, qw, kw, vt);
  attn_kernel<<<BH_ * 8, 256, 0, stream>>>(qw, kw, vt, Pb, mask, (float*)d_out);
}

// Round 5
// 155.411 us; speedup vs baseline: 1.3387x; 1.1184x over previous
//
#include <hip/hip_runtime.h>
#include <stdint.h>

// ---- problem constants ----
#define B_   8
#define SQ_  512
#define SK_  512
#define H_   768
#define NH_  12
#define DH_  64
#define BH_  (B_*NH_)          // 96 (b,h) pairs
#define M_   (B_*SQ_)          // 4096 rows for both hidden and context
#define NTOT (3*H_)            // 2304 fused QKV output columns

typedef __attribute__((ext_vector_type(8))) short short8;
typedef __attribute__((ext_vector_type(4))) float floatx4;
typedef __attribute__((ext_vector_type(4))) unsigned int uint4v;
typedef __attribute__((ext_vector_type(4))) unsigned short ushort4v;

#define MFMA16(a, b, c) __builtin_amdgcn_mfma_f32_16x16x32_bf16((a), (b), (c), 0, 0, 0)

__device__ __forceinline__ unsigned short f2b(float f) {   // fp32 -> bf16 bits (RNE)
  union { float f; unsigned u; } c; c.f = f;
  unsigned r = (c.u + 0x7fffu + ((c.u >> 16) & 1u)) >> 16;
  return (unsigned short)r;
}
__device__ __forceinline__ float b2f(unsigned short u) {   // bf16 bits -> fp32
  union { float f; unsigned u; } c; c.u = ((unsigned)u) << 16;
  return c.f;
}
__device__ __forceinline__ short8 ld8(const unsigned short* p) {  // 16B vector load
  union { uint4v u; short8 s; } c;
  c.u = *(const uint4v*)p;
  return c.s;
}

// ---------------------------------------------------------------------------
// Kernel 1: pack fp32 inputs -> bf16 workspace (hidden, context, W, pos, biases)
// ---------------------------------------------------------------------------
#define SEG_X   (M_*H_)          // 3145728 (hidden)
#define SEG_XC  (2*SEG_X)        // 6291456 (end of context)
#define SEG_W1  (H_*H_)          // 589824
#define SEG_WE  (SEG_XC + 3*SEG_W1)   // 8060928
#define SEG_BE  (SEG_WE + NTOT)  // 8063232
#define SEG_PE  (SEG_BE + SQ_*DH_)    // 8096000 (pos bf16)

__global__ __launch_bounds__(256) void pack_kernel(
    const float* __restrict__ hid, const float* __restrict__ ctx,
    const float* __restrict__ Wq, const float* __restrict__ Wk, const float* __restrict__ Wv,
    const float* __restrict__ bq, const float* __restrict__ bk, const float* __restrict__ bv,
    const float* __restrict__ pos,
    unsigned short* __restrict__ Xh, unsigned short* __restrict__ Xc,
    unsigned short* __restrict__ Wa, float* __restrict__ Ba,
    unsigned short* __restrict__ Pb)
{
  int i = (blockIdx.x * 256 + threadIdx.x) * 4;
  if (i < SEG_X) {
    floatx4 v = *(const floatx4*)(hid + i);
    ushort4v o = { f2b(v.x), f2b(v.y), f2b(v.z), f2b(v.w) };
    *(ushort4v*)(Xh + i) = o;
  } else if (i < SEG_XC) {
    int j = i - SEG_X;
    floatx4 v = *(const floatx4*)(ctx + j);
    ushort4v o = { f2b(v.x), f2b(v.y), f2b(v.z), f2b(v.w) };
    *(ushort4v*)(Xc + j) = o;
  } else if (i < SEG_WE) {
    int j = i - SEG_XC;
    const float* src; int o;
    if (j < SEG_W1)        { src = Wq; o = j; }
    else if (j < 2*SEG_W1) { src = Wk; o = j - SEG_W1; }
    else                   { src = Wv; o = j - 2*SEG_W1; }
    floatx4 v = *(const floatx4*)(src + o);
    ushort4v ov = { f2b(v.x), f2b(v.y), f2b(v.z), f2b(v.w) };
    *(ushort4v*)(Wa + j) = ov;
  } else if (i < SEG_BE) {
    int j = i - SEG_WE;
    #pragma unroll
    for (int t = 0; t < 4; ++t) {
      int jj = j + t;
      float v = (jj < H_) ? bq[jj] : (jj < 2*H_) ? bk[jj - H_] : bv[jj - 2*H_];
      Ba[jj] = v;
    }
  } else if (i < SEG_PE) {
    int j = i - SEG_BE;
    floatx4 v = *(const floatx4*)(pos + j);
    ushort4v o = { f2b(v.x), f2b(v.y), f2b(v.z), f2b(v.w) };
    *(ushort4v*)(Pb + j) = o;
  }
}

// ---------------------------------------------------------------------------
// Kernel 2: fused QKV projection GEMM (bf16 MFMA), M=4096 x N=2304 x K=768
//   + global-load prefetch behind MFMA phase
//   + XCD-swizzled tile mapping (8 regions of 8bm x 9bn; region = bx&7)
// ---------------------------------------------------------------------------
__global__ __launch_bounds__(256) void qkv_gemm(
    const unsigned short* __restrict__ Xh, const unsigned short* __restrict__ Xc,
    const unsigned short* __restrict__ W,  const float* __restrict__ bias,
    const unsigned short* __restrict__ Pb,
    unsigned short* __restrict__ qw, unsigned short* __restrict__ kw,
    unsigned short* __restrict__ vt)
{
  __shared__ unsigned short As[128][72];
  __shared__ unsigned short Bs[128][72];

  int bx = blockIdx.x;
  int xcd = bx & 7, j = bx >> 3;            // j in [0,72)
  int bm = (xcd >> 1) * 8 + j / 9;          // 32 m-tiles
  int bn = (xcd & 1) * 9 + j % 9;           // 18 n-tiles
  const unsigned short* X = (bn < 6) ? Xh : Xc;
  bool isV = (bn >= 12);
  int m0 = bm * 128, n0 = bn * 128;

  int tid = threadIdx.x;
  int lane = tid & 63, wave = tid >> 6;
  int wm = (wave & 1) * 64, wn = (wave >> 1) * 64;
  int lc16 = lane & 15, quad = lane >> 4, kk = quad * 8;
  int srow = tid >> 3, sch = (tid & 7) * 8;   // staging: 32 rows x 8 chunks of 8

  unsigned short (*TA)[72] = isV ? As : Bs;
  unsigned short (*TB)[72] = isV ? Bs : As;
  int oa = isV ? wm : wn;
  int ob = isV ? wn : wm;

  floatx4 acc[4][4];
  #pragma unroll
  for (int i = 0; i < 4; ++i)
    #pragma unroll
    for (int jj = 0; jj < 4; ++jj) acc[i][jj] = (floatx4){0.f, 0.f, 0.f, 0.f};

  uint4v a[4], b[4];
  #pragma unroll
  for (int rp = 0; rp < 4; ++rp) {
    a[rp] = *(const uint4v*)&X[(m0 + srow + rp * 32) * H_ + sch];
    b[rp] = *(const uint4v*)&W[(n0 + srow + rp * 32) * H_ + sch];
  }

  for (int k0 = 0; k0 < H_; k0 += 64) {
    __syncthreads();
    #pragma unroll
    for (int rp = 0; rp < 4; ++rp) {
      *(uint4v*)&As[srow + rp * 32][sch] = a[rp];
      *(uint4v*)&Bs[srow + rp * 32][sch] = b[rp];
    }
    __syncthreads();

    if (k0 + 64 < H_) {
      #pragma unroll
      for (int rp = 0; rp < 4; ++rp) {
        a[rp] = *(const uint4v*)&X[(m0 + srow + rp * 32) * H_ + k0 + 64 + sch];
        b[rp] = *(const uint4v*)&W[(n0 + srow + rp * 32) * H_ + k0 + 64 + sch];
      }
    }

    #pragma unroll
    for (int s = 0; s < 2; ++s) {
      short8 af[4], bf[4];
      #pragma unroll
      for (int i = 0; i < 4; ++i) af[i] = ld8(&TA[oa + i * 16 + lc16][s * 32 + kk]);
      #pragma unroll
      for (int i = 0; i < 4; ++i) bf[i] = ld8(&TB[ob + i * 16 + lc16][s * 32 + kk]);
      #pragma unroll
      for (int mi = 0; mi < 4; ++mi)
        #pragma unroll
        for (int ni = 0; ni < 4; ++ni)
          acc[mi][ni] = MFMA16(af[mi], bf[ni], acc[mi][ni]);
    }
  }

  if (!isV) {
    #pragma unroll
    for (int mi = 0; mi < 4; ++mi) {
      #pragma unroll
      for (int ni = 0; ni < 4; ++ni) {
        int gn0 = n0 + wn + mi * 16 + quad * 4;     // 4 consecutive features
        int gs  = m0 + wm + ni * 16 + lc16;         // sequence index
        int bidx = gs >> 9, s0 = gs & 511;
        floatx4 bv4 = *(const floatx4*)&bias[gn0];
        ushort4v o;
        if (gn0 < H_) {                              // Q
          int h = gn0 >> 6, d0 = gn0 & 63;
          #pragma unroll
          for (int r = 0; r < 4; ++r) o[r] = f2b(acc[mi][ni][r] + bv4[r]);
          *(ushort4v*)(qw + (((bidx * NH_ + h) << 9) + s0) * DH_ + d0) = o;
        } else {                                     // K (+ bf16 pos_k)
          int g = gn0 - H_;
          int h = g >> 6, d0 = g & 63;
          ushort4v pk = *(const ushort4v*)(Pb + s0 * DH_ + d0);
          #pragma unroll
          for (int r = 0; r < 4; ++r) o[r] = f2b(acc[mi][ni][r] + bv4[r] + b2f(pk[r]));
          *(ushort4v*)(kw + (((bidx * NH_ + h) << 9) + s0) * DH_ + d0) = o;
        }
      }
    }
  } else {
    #pragma unroll
    for (int mi = 0; mi < 4; ++mi) {
      #pragma unroll
      for (int ni = 0; ni < 4; ++ni) {
        int gm0 = m0 + wm + mi * 16 + quad * 4;
        int gn  = n0 + wn + ni * 16 + lc16;
        float bv = bias[gn];
        int bidx = gm0 >> 9, s0 = gm0 & 511;
        int g = gn - 2 * H_;
        int h = g >> 6, d = g & 63;
        ushort4v pk;
        #pragma unroll
        for (int r = 0; r < 4; ++r) pk[r] = f2b(acc[mi][ni][r] + bv);
        *(ushort4v*)(vt + ((bidx * NH_ + h) * DH_ + d) * SK_ + s0) = pk;
      }
    }
  }
}

// ---------------------------------------------------------------------------
// Kernel 3: attention, softmax fused into QK epilogue (no max pass).
//   block index: bh = bx % 96, qt = bx / 96  -> all 8 q-tiles of one bh share
//   bx mod 8 (round-robin XCD) -> K/V stay L2-resident across q-tiles.
//   Double-buffered prob chunks (one barrier per chunk); K/pos frag loads
//   software-pipelined one step ahead; V frags issued before QK phase.
// ---------------------------------------------------------------------------
#define SCALE2 0.18033688011112042f   // (1/8) * log2(e)
#define CPAD 136                      // chunk row stride (128 + 8)

__global__ __launch_bounds__(256) void attn_kernel(
    const unsigned short* __restrict__ qw, const unsigned short* __restrict__ kw,
    const unsigned short* __restrict__ vt, const unsigned short* __restrict__ posb,
    const int* __restrict__ mask, float* __restrict__ out)
{
  __shared__ unsigned short Sc[2][64][CPAD];  // bf16 probs, double-buffered chunks
  __shared__ float mb2[SK_];                  // mask bias in exp2 domain
  __shared__ float red[64][4];                // per-wave row-sum partials

  int bx = blockIdx.x;
  int bh = bx % 96, qt = bx / 96;          // XCD-friendly: bx%8 == bh%8
  int b = bh / NH_, h = bh - b * NH_;
  int tid = threadIdx.x, lane = tid & 63, wave = tid >> 6;
  int lc16 = lane & 15, quad = lane >> 4, kk = quad * 8;

  for (int i = tid; i < SK_; i += 256)
    mb2[i] = mask[(b << 9) + i] ? 0.0f : -100000.0f;

  // B-operand frags (held all QK phases): 4 row-tiles x (2 q + 2 pos_q)
  const unsigned short* qbase = qw + ((bh << 9) + qt * 64) * DH_;
  const unsigned short* pqb   = posb + (qt * 64) * DH_;
  short8 aq[4][2], ap[4][2];
  #pragma unroll
  for (int rt = 0; rt < 4; ++rt) {
    const unsigned short* qr = qbase + (rt * 16 + lc16) * DH_;
    const unsigned short* pr = pqb + (rt * 16 + lc16) * DH_;
    aq[rt][0] = ld8(qr + kk);
    aq[rt][1] = ld8(qr + 32 + kk);
    ap[rt][0] = ld8(pr + kk);
    ap[rt][1] = ld8(pr + 32 + kk);
  }

  const unsigned short* kwb = kw + ((bh << 9)) * DH_;
  const unsigned short* vb0 = vt + (bh * DH_ + wave * 16 + lc16) * SK_;
  float rs[4] = {0.f, 0.f, 0.f, 0.f};      // per-lane row-sum partials
  floatx4 o[4];
  #pragma unroll
  for (int i = 0; i < 4; ++i) o[i] = (floatx4){0.f, 0.f, 0.f, 0.f};

  // prefetch K/pos step 0
  short8 cb0, cb1, cp0, cp1, nb0, nb1, np0, np1;
  {
    int kcol = wave * 32;
    const unsigned short* kb = kwb + kcol * DH_;
    const unsigned short* pb = posb + kcol * DH_;
    cb0 = ld8(kb + lc16 * DH_ + kk);
    cb1 = ld8(kb + lc16 * DH_ + 32 + kk);
    cp0 = ld8(pb + lc16 * DH_ + kk);
    cp1 = ld8(pb + lc16 * DH_ + 32 + kk);
  }

  __syncthreads();   // mb2 ready

  for (int chunk = 0; chunk < 4; ++chunk) {
    unsigned short (*S)[CPAD] = Sc[chunk & 1];

    // V frags for this chunk: issue early, consumed after the barrier
    short8 vf[4];
    #pragma unroll
    for (int ks = 0; ks < 4; ++ks) vf[ks] = ld8(vb0 + chunk * 128 + ks * 32 + kk);

    // ---- QK + exp: wave owns chunk-local cols [wave*32, wave*32+32) ----
    #pragma unroll
    for (int ct = 0; ct < 2; ++ct) {
      int s = chunk * 2 + ct;
      if (s < 7) {   // prefetch next step's K/pos frags
        int kcol = ((s + 1) >> 1) * 128 + wave * 32 + ((s + 1) & 1) * 16;
        const unsigned short* kb = kwb + kcol * DH_;
        const unsigned short* pb = posb + kcol * DH_;
        nb0 = ld8(kb + lc16 * DH_ + kk);
        nb1 = ld8(kb + lc16 * DH_ + 32 + kk);
        np0 = ld8(pb + lc16 * DH_ + kk);
        np1 = ld8(pb + lc16 * DH_ + 32 + kk);
      }
      int kcol = chunk * 128 + wave * 32 + ct * 16;
      floatx4 mk = *(const floatx4*)&mb2[kcol + quad * 4];
      floatx4 c[4];
      #pragma unroll
      for (int rt = 0; rt < 4; ++rt) {
        c[rt] = (floatx4){0.f, 0.f, 0.f, 0.f};
        c[rt] = MFMA16(cb0, aq[rt][0], c[rt]);   // A=K-tile, B=Q-rows
        c[rt] = MFMA16(cb1, aq[rt][1], c[rt]);
        c[rt] = MFMA16(cp0, ap[rt][0], c[rt]);
        c[rt] = MFMA16(cp1, ap[rt][1], c[rt]);
      }
      int lcol = wave * 32 + ct * 16 + quad * 4;   // chunk-local col base
      #pragma unroll
      for (int rt = 0; rt < 4; ++rt) {
        ushort4v pv;
        float sum = 0.f;
        #pragma unroll
        for (int r = 0; r < 4; ++r) {
          float e = __builtin_exp2f(c[rt][r] * SCALE2 + mk[r]);
          sum += e;
          pv[r] = f2b(e);
        }
        rs[rt] += sum;
        *(ushort4v*)&S[rt * 16 + lc16][lcol] = pv;
      }
      cb0 = nb0; cb1 = nb1; cp0 = np0; cp1 = np1;
    }
    __syncthreads();   // probs chunk ready (also: prior chunk fully consumed)

    // ---- PV over this chunk: wave owns d-slice [wave*16, +16) ----
    #pragma unroll
    for (int ks = 0; ks < 4; ++ks) {
      #pragma unroll
      for (int rt = 0; rt < 4; ++rt) {
        short8 pa = ld8(&S[rt * 16 + lc16][ks * 32 + kk]);
        o[rt] = MFMA16(pa, vf[ks], o[rt]);
      }
    }
    // no second barrier: next chunk writes the other Sc buffer
  }

  // ---- row-sum: reduce across quads, then across waves via LDS ----
  #pragma unroll
  for (int rt = 0; rt < 4; ++rt) {
    rs[rt] += __shfl_xor(rs[rt], 16, 64);
    rs[rt] += __shfl_xor(rs[rt], 32, 64);
  }
  if (quad == 0) {
    #pragma unroll
    for (int rt = 0; rt < 4; ++rt) red[rt * 16 + lc16][wave] = rs[rt];
  }
  __syncthreads();

  #pragma unroll
  for (int rt = 0; rt < 4; ++rt) {
    #pragma unroll
    for (int r = 0; r < 4; ++r) {
      int sl = rt * 16 + quad * 4 + r;
      float inv = 1.0f / (red[sl][0] + red[sl][1] + red[sl][2] + red[sl][3]);
      int s = qt * 64 + sl;
      out[((b << 9) + s) * H_ + h * DH_ + wave * 16 + lc16] = o[rt][r] * inv;
    }
  }
}

// ---------------------------------------------------------------------------
// host launcher
// ---------------------------------------------------------------------------
extern "C" void kernel_launch(void* const* d_in, const int* in_sizes, int n_in,
                              void* d_out, int out_size, void* d_ws, size_t ws_size,
                              hipStream_t stream) {
  (void)in_sizes; (void)n_in; (void)out_size; (void)ws_size;
  const float* hid  = (const float*)d_in[0];
  const float* ctx  = (const float*)d_in[1];
  const int*   mask = (const int*)d_in[2];
  const float* Wq   = (const float*)d_in[3];
  const float* bq   = (const float*)d_in[4];
  const float* Wk   = (const float*)d_in[5];
  const float* bk   = (const float*)d_in[6];
  const float* Wv   = (const float*)d_in[7];
  const float* bv   = (const float*)d_in[8];
  const float* pos  = (const float*)d_in[9];

  char* ws = (char*)d_ws;
  size_t off = 0;
  auto alloc = [&](size_t bytes) { char* p = ws + off; off = (off + bytes + 255) & ~(size_t)255; return p; };
  unsigned short* Xh = (unsigned short*)alloc((size_t)SEG_X * 2);
  unsigned short* Xc = (unsigned short*)alloc((size_t)SEG_X * 2);
  unsigned short* Wa = (unsigned short*)alloc((size_t)3 * SEG_W1 * 2);
  float*          Ba = (float*)alloc((size_t)NTOT * 4);
  unsigned short* qw = (unsigned short*)alloc((size_t)BH_ * SQ_ * DH_ * 2);
  unsigned short* kw = (unsigned short*)alloc((size_t)BH_ * SK_ * DH_ * 2);
  unsigned short* vt = (unsigned short*)alloc((size_t)BH_ * DH_ * SK_ * 2);
  unsigned short* Pb = (unsigned short*)alloc((size_t)SQ_ * DH_ * 2);

  int pack_blocks = (SEG_PE / 4 + 255) / 256;
  pack_kernel<<<pack_blocks, 256, 0, stream>>>(hid, ctx, Wq, Wk, Wv, bq, bk, bv, pos, Xh, Xc, Wa, Ba, Pb);
  qkv_gemm<<<32 * 18, 256, 0, stream>>>(Xh, Xc, Wa, Ba, Pb, qw, kw, vt);
  attn_kernel<<<BH_ * 8, 256, 0, stream>>>(qw, kw, vt, Pb, mask, (float*)d_out);
}